// Round 1
// baseline (3376.260 us; speedup 1.0000x reference)
//
#include <hip/hip_runtime.h>
#include <math.h>

#define B_ 8
#define S_ 1024
#define D_ 4096
#define DV_ 1024
#define NP_ 576
#define MAXE_ 1599
#define PK_ 588          // 3*14*14
#define IMG_ 336
#define GRID_ 24
#define PATCH_ 14
#define IMAGE_TOKEN_ 32000
#define PAD_TOKEN_ 0
#define NLAYERS_ 32
#define NEXP_ 8
#define NSH_ 2

// ---- output layout (flat float32) ----
// [0]                      current_layer
// [1 .. 1+B*MAXE*D)        final_emb
// then B*MAXE              final_attn
// then B*MAXE              final_labels
// then 32*MAXE*8           router_logits (zeros)
// then 32*MAXE*2           shared_router_logits (zeros)
#define EMB_ELEMS ((size_t)B_ * MAXE_ * D_)
#define OFF_EMB   ((size_t)1)
#define OFF_ATTN  (OFF_EMB + EMB_ELEMS)
#define OFF_LAB   (OFF_ATTN + (size_t)B_ * MAXE_)
#define OFF_ROUTER (OFF_LAB + (size_t)B_ * MAXE_)
#define ROUTER_ELEMS ((size_t)NLAYERS_ * MAXE_ * (NEXP_ + NSH_))

__global__ void fill_tail_kernel(float* __restrict__ out) {
    size_t i = (size_t)blockIdx.x * blockDim.x + threadIdx.x;
    if (i == 0) out[0] = 0.0f;
    for (size_t j = i; j < ROUTER_ELEMS; j += (size_t)gridDim.x * blockDim.x)
        out[OFF_ROUTER + j] = 0.0f;
}

// Single block, 512 threads (8 waves). Wave w handles batch row w.
__global__ __launch_bounds__(512) void merge_kernel(
    const int* __restrict__ input_ids, const int* __restrict__ attn_mask,
    const int* __restrict__ labels, float* __restrict__ out,
    int* __restrict__ src_index, int* __restrict__ img_pos)
{
    __shared__ int sh_nbpad[B_];
    __shared__ int sh_shift[B_];
    __shared__ int sh_nqual[B_];
    __shared__ int sh_leftpad;
    float* out_attn = out + OFF_ATTN;
    float* out_lab  = out + OFF_LAB;
    const int tid = threadIdx.x;

    // phase 0: defaults
    for (int i = tid; i < B_ * MAXE_; i += blockDim.x) {
        src_index[i] = -1;          // -1 = hole (zero), >=0 = text token t, -2 = image
        out_attn[i] = 0.0f;
        out_lab[i] = -100.0f;
    }
    for (int i = tid; i < B_ * NP_; i += blockDim.x) img_pos[i] = -1;
    if (tid == 0) {
        int anypad = 0;
        for (int b = 0; b < B_; b++)
            if (input_ids[b * S_ + S_ - 1] == PAD_TOKEN_) anypad = 1;
        sh_leftpad = !anypad;
    }
    __syncthreads();

    const int wave = tid >> 6;
    const int lane = tid & 63;
    const unsigned long long below = (1ull << lane) - 1ull;

    if (wave < B_) {
        const int b = wave;
        // pass A: count specials -> nb_pad, shift, qualifying-hole count
        int nspec = 0;
        for (int c = 0; c < S_; c += 64) {
            int id = input_ids[b * S_ + c + lane];
            nspec += __popcll(__ballot(id == IMAGE_TOKEN_));
        }
        int nb_pad = MAXE_ - S_ - (NP_ - 1) * nspec;
        int shift = sh_leftpad ? nb_pad : 0;
        int nholes = MAXE_ - (S_ - nspec);
        int nq = nholes - nb_pad; if (nq < 0) nq = 0;
        if (lane == 0) { sh_nbpad[b] = nb_pad; sh_shift[b] = shift; sh_nqual[b] = nq; }
        // pass B: scatter text tokens
        int carry = 0;
        for (int c = 0; c < S_; c += 64) {
            int t = c + lane;
            int id = input_ids[b * S_ + t];
            int spec = (id == IMAGE_TOKEN_);
            unsigned long long m = __ballot(spec);
            int nbefore = carry + __popcll(m & below);
            if (!spec) {
                int pos = t + (NP_ - 1) * nbefore + shift;
                if (pos >= 0 && pos < MAXE_) {
                    src_index[b * MAXE_ + pos] = t;
                    out_attn[b * MAXE_ + pos] = (float)attn_mask[b * S_ + t];
                    out_lab[b * MAXE_ + pos]  = (float)labels[b * S_ + t];
                }
            }
            carry += __popcll(m);
        }
    }
    __syncthreads();

    // phase 3: assign image features to qualifying holes
    if (wave < B_) {
        const int b = wave;
        int offs = 0;
        for (int r = 0; r < b; r++) offs += sh_nqual[r];
        const int nb_pad = sh_nbpad[b];
        int hcarry = 0;
        for (int c = 0; c < MAXE_; c += 64) {
            int p = c + lane;
            int flag = 0;
            if (p < MAXE_) flag = (src_index[b * MAXE_ + p] == -1);
            unsigned long long m = __ballot(flag);
            int h = hcarry + __popcll(m & below);
            if (flag && h >= nb_pad) {
                int g = offs + (h - nb_pad);
                if (g > B_ * NP_ - 1) g = B_ * NP_ - 1;
                if (g < 0) g = 0;
                img_pos[g] = b * MAXE_ + p;
                src_index[b * MAXE_ + p] = -2;
                out_attn[b * MAXE_ + p] = 1.0f;
            }
            hcarry += __popcll(m);
        }
    }
}

__global__ void patchify_kernel(const float* __restrict__ pix, float* __restrict__ x) {
    int i = blockIdx.x * blockDim.x + threadIdx.x;
    const int total = B_ * NP_ * PK_;
    if (i >= total) return;
    int q = i % PK_;
    int t = (i / PK_) % NP_;
    int n = i / (PK_ * NP_);
    int c = q / (PATCH_ * PATCH_);
    int r = q % (PATCH_ * PATCH_);
    int py = r / PATCH_, px = r % PATCH_;
    int gy = t / GRID_, gx = t % GRID_;
    x[i] = pix[(((size_t)n * 3 + c) * IMG_ + gy * PATCH_ + py) * IMG_ + gx * PATCH_ + px];
}

// C = A(MxK) * B(KxN) + bias ; mode 0 = plain, 1 = gelu(tanh), 2 = scatter rows via pos_map
__global__ __launch_bounds__(256) void sgemm_kernel(
    const float* __restrict__ A, const float* __restrict__ Bm,
    const float* __restrict__ bias, float* __restrict__ C,
    const int* __restrict__ pos_map, int M, int N, int K, int mode)
{
    __shared__ float As[8][128 + 4];
    __shared__ float Bs[8][128 + 4];
    const int tid = threadIdx.x;
    const int tx = tid & 15;
    const int ty = tid >> 4;
    const int row0 = blockIdx.y * 128;
    const int col0 = blockIdx.x * 128;
    float acc[8][8];
#pragma unroll
    for (int i = 0; i < 8; i++)
#pragma unroll
        for (int j = 0; j < 8; j++) acc[i][j] = 0.0f;

    const int ar = tid >> 1;           // 0..127
    const int ak = (tid & 1) * 4;      // 0 or 4
    const int bk = tid >> 5;           // 0..7
    const int bn = (tid & 31) * 4;     // 0..124

    for (int k0 = 0; k0 < K; k0 += 8) {
        float4 av = make_float4(0.f, 0.f, 0.f, 0.f);
        {
            int r = row0 + ar;
            int kb = k0 + ak;
            if (r < M) {
                if (kb + 4 <= K) {
                    av = *(const float4*)(A + (size_t)r * K + kb);
                } else {
                    float tmp[4] = {0.f, 0.f, 0.f, 0.f};
                    for (int u = 0; u < 4; u++)
                        if (kb + u < K) tmp[u] = A[(size_t)r * K + kb + u];
                    av = make_float4(tmp[0], tmp[1], tmp[2], tmp[3]);
                }
            }
        }
        As[ak + 0][ar] = av.x; As[ak + 1][ar] = av.y;
        As[ak + 2][ar] = av.z; As[ak + 3][ar] = av.w;

        float4 bv = make_float4(0.f, 0.f, 0.f, 0.f);
        {
            int kr = k0 + bk;
            if (kr < K) bv = *(const float4*)(Bm + (size_t)kr * N + col0 + bn);
        }
        *(float4*)&Bs[bk][bn] = bv;
        __syncthreads();

#pragma unroll
        for (int kk = 0; kk < 8; kk++) {
            float am[8], bb[8];
#pragma unroll
            for (int i = 0; i < 8; i++) am[i] = As[kk][ty * 8 + i];
#pragma unroll
            for (int j = 0; j < 8; j++) bb[j] = Bs[kk][tx * 8 + j];
#pragma unroll
            for (int i = 0; i < 8; i++)
#pragma unroll
                for (int j = 0; j < 8; j++)
                    acc[i][j] = fmaf(am[i], bb[j], acc[i][j]);
        }
        __syncthreads();
    }

    // epilogue
#pragma unroll
    for (int i = 0; i < 8; i++) {
        int r = row0 + ty * 8 + i;
        if (r >= M) continue;
        int c0 = col0 + tx * 8;
        float v[8];
#pragma unroll
        for (int j = 0; j < 8; j++) {
            float x = acc[i][j] + bias[c0 + j];
            if (mode == 1) {
                float u = 0.7978845608028654f * (x + 0.044715f * x * x * x);
                x = 0.5f * x * (1.0f + tanhf(u));
            }
            v[j] = x;
        }
        if (mode == 2) {
            int outr = pos_map[r];
            if (outr < 0) continue;
            float* dst = C + (size_t)outr * N + c0;   // 16B-misaligned base: scalar stores
#pragma unroll
            for (int j = 0; j < 8; j++) dst[j] = v[j];
        } else {
            float* dst = C + (size_t)r * N + c0;
            *(float4*)dst = make_float4(v[0], v[1], v[2], v[3]);
            *(float4*)(dst + 4) = make_float4(v[4], v[5], v[6], v[7]);
        }
    }
}

__global__ __launch_bounds__(256) void scatter_text_kernel(
    const int* __restrict__ src_index, const int* __restrict__ input_ids,
    const float* __restrict__ embed, float* __restrict__ final_emb)
{
    int row = blockIdx.x;                 // 0..B*MAXE-1
    int src = src_index[row];
    if (src == -2) return;                // image position: written by GEMM3
    float* dst = final_emb + (size_t)row * D_;
    if (src >= 0) {
        int b = row / MAXE_;
        int tok = input_ids[b * S_ + src];
        const float* s = embed + (size_t)tok * D_;
        for (int i = threadIdx.x; i < D_; i += blockDim.x) dst[i] = s[i];
    } else {
        for (int i = threadIdx.x; i < D_; i += blockDim.x) dst[i] = 0.0f;
    }
}

extern "C" void kernel_launch(void* const* d_in, const int* in_sizes, int n_in,
                              void* d_out, int out_size, void* d_ws, size_t ws_size,
                              hipStream_t stream)
{
    const int*   input_ids = (const int*)d_in[0];
    const float* pixel     = (const float*)d_in[1];
    const int*   attn      = (const int*)d_in[2];
    const int*   labels    = (const int*)d_in[3];
    const float* embed     = (const float*)d_in[4];
    // d_in[5] = cls_emb (unused: reference drops the CLS row)
    const float* patch_w   = (const float*)d_in[6];
    const float* patch_b   = (const float*)d_in[7];
    const float* w1        = (const float*)d_in[8];
    const float* b1        = (const float*)d_in[9];
    const float* w2        = (const float*)d_in[10];
    const float* b2        = (const float*)d_in[11];
    float* out = (float*)d_out;

    // workspace layout
    char* w = (char*)d_ws;
    int* src_index = (int*)w;                                   // B*MAXE ints
    int* img_pos   = (int*)(w + 51200);                         // B*NP ints
    float* xbuf = (float*)(w + 51200 + 18432);                  // B*NP*588 f32
    float* hbuf = xbuf + (size_t)B_ * NP_ * PK_;                // B*NP*1024 f32
    float* g1   = hbuf + (size_t)B_ * NP_ * DV_;                // B*NP*4096 f32

    fill_tail_kernel<<<2048, 256, 0, stream>>>(out);
    merge_kernel<<<1, 512, 0, stream>>>(input_ids, attn, labels, out, src_index, img_pos);

    {
        int total = B_ * NP_ * PK_;
        patchify_kernel<<<(total + 255) / 256, 256, 0, stream>>>(pixel, xbuf);
    }
    const int M = B_ * NP_;  // 4608
    // GEMM1: x(4608x588) @ patch_w(588x1024) + patch_b -> h
    sgemm_kernel<<<dim3(DV_ / 128, (M + 127) / 128), 256, 0, stream>>>(
        xbuf, patch_w, patch_b, hbuf, nullptr, M, DV_, PK_, 0);
    // GEMM2: gelu(h @ w1 + b1) -> g1
    sgemm_kernel<<<dim3(D_ / 128, (M + 127) / 128), 256, 0, stream>>>(
        hbuf, w1, b1, g1, nullptr, M, D_, DV_, 1);
    // GEMM3: g1 @ w2 + b2 -> scattered into final_emb rows via img_pos
    sgemm_kernel<<<dim3(D_ / 128, (M + 127) / 128), 256, 0, stream>>>(
        g1, w2, b2, out + OFF_EMB, img_pos, M, D_, D_, 2);

    scatter_text_kernel<<<B_ * MAXE_, 256, 0, stream>>>(src_index, input_ids, embed, out + OFF_EMB);
}

// Round 2
// 1217.528 us; speedup vs baseline: 2.7730x; 2.7730x over previous
//
#include <hip/hip_runtime.h>
#include <math.h>

#define B_ 8
#define S_ 1024
#define D_ 4096
#define DV_ 1024
#define NP_ 576
#define MAXE_ 1599
#define PK_ 588          // 3*14*14
#define IMG_ 336
#define GRID_ 24
#define PATCH_ 14
#define IMAGE_TOKEN_ 32000
#define PAD_TOKEN_ 0
#define NLAYERS_ 32
#define NEXP_ 8
#define NSH_ 2

// ---- output layout (flat float32) ----
#define EMB_ELEMS ((size_t)B_ * MAXE_ * D_)
#define OFF_EMB   ((size_t)1)
#define OFF_ATTN  (OFF_EMB + EMB_ELEMS)
#define OFF_LAB   (OFF_ATTN + (size_t)B_ * MAXE_)
#define OFF_ROUTER (OFF_LAB + (size_t)B_ * MAXE_)
#define ROUTER_ELEMS ((size_t)NLAYERS_ * MAXE_ * (NEXP_ + NSH_))

typedef __bf16 bf16x8 __attribute__((ext_vector_type(8)));
typedef float  f32x4  __attribute__((ext_vector_type(4)));
typedef unsigned short ushort_t;

__device__ __forceinline__ unsigned short f2bf(float f) {
    unsigned u = __float_as_uint(f);
    u += 0x7fffu + ((u >> 16) & 1u);   // RNE
    return (unsigned short)(u >> 16);
}

__device__ __forceinline__ void async_copy16(const void* g, void* l) {
    __builtin_amdgcn_global_load_lds(
        (const __attribute__((address_space(1))) void*)g,
        (__attribute__((address_space(3))) void*)l, 16, 0, 0);
}

__global__ void fill_tail_kernel(float* __restrict__ out) {
    size_t i = (size_t)blockIdx.x * blockDim.x + threadIdx.x;
    if (i == 0) out[0] = 0.0f;
    for (size_t j = i; j < ROUTER_ELEMS; j += (size_t)gridDim.x * blockDim.x)
        out[OFF_ROUTER + j] = 0.0f;
}

// Single block, 512 threads (8 waves). Wave w handles batch row w.
__global__ __launch_bounds__(512) void merge_kernel(
    const int* __restrict__ input_ids, const int* __restrict__ attn_mask,
    const int* __restrict__ labels, float* __restrict__ out,
    int* __restrict__ src_index, int* __restrict__ img_pos)
{
    __shared__ int sh_nbpad[B_];
    __shared__ int sh_shift[B_];
    __shared__ int sh_nqual[B_];
    __shared__ int sh_leftpad;
    float* out_attn = out + OFF_ATTN;
    float* out_lab  = out + OFF_LAB;
    const int tid = threadIdx.x;

    for (int i = tid; i < B_ * MAXE_; i += blockDim.x) {
        src_index[i] = -1;
        out_attn[i] = 0.0f;
        out_lab[i] = -100.0f;
    }
    for (int i = tid; i < B_ * NP_; i += blockDim.x) img_pos[i] = -1;
    if (tid == 0) {
        int anypad = 0;
        for (int b = 0; b < B_; b++)
            if (input_ids[b * S_ + S_ - 1] == PAD_TOKEN_) anypad = 1;
        sh_leftpad = !anypad;
    }
    __syncthreads();

    const int wave = tid >> 6;
    const int lane = tid & 63;
    const unsigned long long below = (1ull << lane) - 1ull;

    if (wave < B_) {
        const int b = wave;
        int nspec = 0;
        for (int c = 0; c < S_; c += 64) {
            int id = input_ids[b * S_ + c + lane];
            nspec += __popcll(__ballot(id == IMAGE_TOKEN_));
        }
        int nb_pad = MAXE_ - S_ - (NP_ - 1) * nspec;
        int shift = sh_leftpad ? nb_pad : 0;
        int nholes = MAXE_ - (S_ - nspec);
        int nq = nholes - nb_pad; if (nq < 0) nq = 0;
        if (lane == 0) { sh_nbpad[b] = nb_pad; sh_shift[b] = shift; sh_nqual[b] = nq; }
        int carry = 0;
        for (int c = 0; c < S_; c += 64) {
            int t = c + lane;
            int id = input_ids[b * S_ + t];
            int spec = (id == IMAGE_TOKEN_);
            unsigned long long m = __ballot(spec);
            int nbefore = carry + __popcll(m & below);
            if (!spec) {
                int pos = t + (NP_ - 1) * nbefore + shift;
                if (pos >= 0 && pos < MAXE_) {
                    src_index[b * MAXE_ + pos] = t;
                    out_attn[b * MAXE_ + pos] = (float)attn_mask[b * S_ + t];
                    out_lab[b * MAXE_ + pos]  = (float)labels[b * S_ + t];
                }
            }
            carry += __popcll(m);
        }
    }
    __syncthreads();

    if (wave < B_) {
        const int b = wave;
        int offs = 0;
        for (int r = 0; r < b; r++) offs += sh_nqual[r];
        const int nb_pad = sh_nbpad[b];
        int hcarry = 0;
        for (int c = 0; c < MAXE_; c += 64) {
            int p = c + lane;
            int flag = 0;
            if (p < MAXE_) flag = (src_index[b * MAXE_ + p] == -1);
            unsigned long long m = __ballot(flag);
            int h = hcarry + __popcll(m & below);
            if (flag && h >= nb_pad) {
                int g = offs + (h - nb_pad);
                if (g > B_ * NP_ - 1) g = B_ * NP_ - 1;
                if (g < 0) g = 0;
                img_pos[g] = b * MAXE_ + p;
                src_index[b * MAXE_ + p] = -2;
                out_attn[b * MAXE_ + p] = 1.0f;
            }
            hcarry += __popcll(m);
        }
    }
}

__global__ void patchify_kernel(const float* __restrict__ pix, float* __restrict__ x) {
    int i = blockIdx.x * blockDim.x + threadIdx.x;
    const int total = B_ * NP_ * PK_;
    if (i >= total) return;
    int q = i % PK_;
    int t = (i / PK_) % NP_;
    int n = i / (PK_ * NP_);
    int c = q / (PATCH_ * PATCH_);
    int r = q % (PATCH_ * PATCH_);
    int py = r / PATCH_, px = r % PATCH_;
    int gy = t / GRID_, gx = t % GRID_;
    x[i] = pix[(((size_t)n * 3 + c) * IMG_ + gy * PATCH_ + py) * IMG_ + gx * PATCH_ + px];
}

// transpose + fp32->bf16 convert: src[R][C] -> dst[C][R]
__global__ __launch_bounds__(256) void transpose_bf16_kernel(
    const float* __restrict__ src, ushort_t* __restrict__ dst, int R, int C)
{
    __shared__ float tile[32][33];
    int c0 = blockIdx.x * 32, r0 = blockIdx.y * 32;
    int tx = threadIdx.x & 31, ty = threadIdx.x >> 5;   // 32 x 8
    for (int i = ty; i < 32; i += 8)
        tile[i][tx] = src[(size_t)(r0 + i) * C + c0 + tx];
    __syncthreads();
    for (int i = ty; i < 32; i += 8)
        dst[(size_t)(c0 + i) * R + r0 + tx] = f2bf(tile[tx][i]);
}

// fp32 SGEMM (for GEMM1, K=588): C = A(MxK)*B(KxN)+bias. mode 0: f32 out, 3: bf16 out
__global__ __launch_bounds__(256) void sgemm_kernel(
    const float* __restrict__ A, const float* __restrict__ Bm,
    const float* __restrict__ bias, float* __restrict__ C, ushort_t* __restrict__ Cb,
    int M, int N, int K, int mode)
{
    __shared__ float As[8][128 + 4];
    __shared__ float Bs[8][128 + 4];
    const int tid = threadIdx.x;
    const int tx = tid & 15;
    const int ty = tid >> 4;
    const int row0 = blockIdx.y * 128;
    const int col0 = blockIdx.x * 128;
    float acc[8][8];
#pragma unroll
    for (int i = 0; i < 8; i++)
#pragma unroll
        for (int j = 0; j < 8; j++) acc[i][j] = 0.0f;

    const int ar = tid >> 1;
    const int ak = (tid & 1) * 4;
    const int bk = tid >> 5;
    const int bn = (tid & 31) * 4;

    for (int k0 = 0; k0 < K; k0 += 8) {
        float4 av = make_float4(0.f, 0.f, 0.f, 0.f);
        {
            int r = row0 + ar;
            int kb = k0 + ak;
            if (r < M) {
                if (kb + 4 <= K) {
                    av = *(const float4*)(A + (size_t)r * K + kb);
                } else {
                    float tmp[4] = {0.f, 0.f, 0.f, 0.f};
                    for (int u = 0; u < 4; u++)
                        if (kb + u < K) tmp[u] = A[(size_t)r * K + kb + u];
                    av = make_float4(tmp[0], tmp[1], tmp[2], tmp[3]);
                }
            }
        }
        As[ak + 0][ar] = av.x; As[ak + 1][ar] = av.y;
        As[ak + 2][ar] = av.z; As[ak + 3][ar] = av.w;

        float4 bv = make_float4(0.f, 0.f, 0.f, 0.f);
        {
            int kr = k0 + bk;
            if (kr < K) bv = *(const float4*)(Bm + (size_t)kr * N + col0 + bn);
        }
        *(float4*)&Bs[bk][bn] = bv;
        __syncthreads();

#pragma unroll
        for (int kk = 0; kk < 8; kk++) {
            float am[8], bb[8];
#pragma unroll
            for (int i = 0; i < 8; i++) am[i] = As[kk][ty * 8 + i];
#pragma unroll
            for (int j = 0; j < 8; j++) bb[j] = Bs[kk][tx * 8 + j];
#pragma unroll
            for (int i = 0; i < 8; i++)
#pragma unroll
                for (int j = 0; j < 8; j++)
                    acc[i][j] = fmaf(am[i], bb[j], acc[i][j]);
        }
        __syncthreads();
    }

#pragma unroll
    for (int i = 0; i < 8; i++) {
        int r = row0 + ty * 8 + i;
        if (r >= M) continue;
        int c0 = col0 + tx * 8;
        float v[8];
#pragma unroll
        for (int j = 0; j < 8; j++) v[j] = acc[i][j] + bias[c0 + j];
        if (mode == 3) {
            ushort_t* dst = Cb + (size_t)r * N + c0;
#pragma unroll
            for (int j = 0; j < 8; j++) dst[j] = f2bf(v[j]);
        } else {
            float* dst = C + (size_t)r * N + c0;
            *(float4*)dst = make_float4(v[0], v[1], v[2], v[3]);
            *(float4*)(dst + 4) = make_float4(v[4], v[5], v[6], v[7]);
        }
    }
}

// bf16 MFMA GEMM, B-transposed: C[M][N] = A[M][K] @ Bt[N][K]^T  (+bias)
// 128x128 tile, BK=32, 256 threads = 4 waves in 2x2, 16x16x32 MFMA.
// mode 1: gelu(acc+bias) -> bf16 outb (row-major MxN)
// mode 2: acc+bias -> f32 outf, row scattered via pos_map
__global__ __launch_bounds__(256) void mfma_gemm_bt(
    const ushort_t* __restrict__ A, const ushort_t* __restrict__ Bt,
    const float* __restrict__ bias, ushort_t* __restrict__ outb,
    float* __restrict__ outf, const int* __restrict__ pos_map,
    int M, int N, int K, int mode)
{
    __shared__ ushort_t As[128 * 32];
    __shared__ ushort_t Bs[128 * 32];
    const int tid  = threadIdx.x;
    const int wave = tid >> 6;
    const int lane = tid & 63;
    const int l16  = lane & 15;
    const int quad = lane >> 4;
    const int wrow = (wave >> 1) * 64;     // wave's 64-row block within tile
    const int wcol = (wave & 1) * 64;      // wave's 64-col block within tile
    const int row0 = blockIdx.y * 128;
    const int col0 = blockIdx.x * 128;

    f32x4 acc[4][4];
#pragma unroll
    for (int i = 0; i < 4; i++)
#pragma unroll
        for (int j = 0; j < 4; j++) acc[i][j] = (f32x4)(0.0f);

    // staging: per wave, 2 issues for A and 2 for B; each issue = 16 rows x 32 cols (1KB)
    const int R0a = wave * 32;             // base row for this wave's two A issues
    const int lr  = lane >> 2;             // row within 16-row group
    const int lc  = (lane & 3) * 8;        // bf16 col offset (16B chunks)

    for (int k0 = 0; k0 < K; k0 += 32) {
#pragma unroll
        for (int i = 0; i < 2; i++) {
            int R0 = R0a + i * 16;
            const ushort_t* ga = A  + (size_t)(row0 + R0 + lr) * K + k0 + lc;
            const ushort_t* gb = Bt + (size_t)(col0 + R0 + lr) * K + k0 + lc;
            async_copy16(ga, &As[R0 * 32]);
            async_copy16(gb, &Bs[R0 * 32]);
        }
        __syncthreads();

        bf16x8 af[4], bf[4];
#pragma unroll
        for (int mt = 0; mt < 4; mt++)
            af[mt] = *(const bf16x8*)&As[(wrow + mt * 16 + l16) * 32 + quad * 8];
#pragma unroll
        for (int nt = 0; nt < 4; nt++)
            bf[nt] = *(const bf16x8*)&Bs[(wcol + nt * 16 + l16) * 32 + quad * 8];
#pragma unroll
        for (int mt = 0; mt < 4; mt++)
#pragma unroll
            for (int nt = 0; nt < 4; nt++)
                acc[mt][nt] = __builtin_amdgcn_mfma_f32_16x16x32_bf16(
                    af[mt], bf[nt], acc[mt][nt], 0, 0, 0);
        __syncthreads();
    }

    // epilogue: D col = lane&15, row = quad*4 + reg
    float bv[4];
#pragma unroll
    for (int nt = 0; nt < 4; nt++) bv[nt] = bias[col0 + wcol + nt * 16 + l16];

#pragma unroll
    for (int mt = 0; mt < 4; mt++) {
#pragma unroll
        for (int r = 0; r < 4; r++) {
            int row = row0 + wrow + mt * 16 + quad * 4 + r;
            if (mode == 2) {
                int orow = pos_map[row];
                if (orow < 0) continue;
#pragma unroll
                for (int nt = 0; nt < 4; nt++) {
                    int col = col0 + wcol + nt * 16 + l16;
                    outf[(size_t)orow * N + col] = acc[mt][nt][r] + bv[nt];
                }
            } else {
#pragma unroll
                for (int nt = 0; nt < 4; nt++) {
                    int col = col0 + wcol + nt * 16 + l16;
                    float x = acc[mt][nt][r] + bv[nt];
                    float u = 0.7978845608028654f * (x + 0.044715f * x * x * x);
                    x = 0.5f * x * (1.0f + tanhf(u));
                    outb[(size_t)row * N + col] = f2bf(x);
                }
            }
        }
    }
}

__global__ __launch_bounds__(256) void scatter_text_kernel(
    const int* __restrict__ src_index, const int* __restrict__ input_ids,
    const float* __restrict__ embed, float* __restrict__ final_emb)
{
    int row = blockIdx.x;
    int src = src_index[row];
    if (src == -2) return;
    float* dst = final_emb + (size_t)row * D_;
    if (src >= 0) {
        int b = row / MAXE_;
        int tok = input_ids[b * S_ + src];
        const float* s = embed + (size_t)tok * D_;
        for (int i = threadIdx.x; i < D_; i += blockDim.x) dst[i] = s[i];
    } else {
        for (int i = threadIdx.x; i < D_; i += blockDim.x) dst[i] = 0.0f;
    }
}

extern "C" void kernel_launch(void* const* d_in, const int* in_sizes, int n_in,
                              void* d_out, int out_size, void* d_ws, size_t ws_size,
                              hipStream_t stream)
{
    const int*   input_ids = (const int*)d_in[0];
    const float* pixel     = (const float*)d_in[1];
    const int*   attn      = (const int*)d_in[2];
    const int*   labels    = (const int*)d_in[3];
    const float* embed     = (const float*)d_in[4];
    const float* patch_w   = (const float*)d_in[6];
    const float* patch_b   = (const float*)d_in[7];
    const float* w1        = (const float*)d_in[8];
    const float* b1        = (const float*)d_in[9];
    const float* w2        = (const float*)d_in[10];
    const float* b2        = (const float*)d_in[11];
    float* out = (float*)d_out;

    // workspace layout
    char* w = (char*)d_ws;
    int* src_index = (int*)w;                                    // 51200 B
    int* img_pos   = (int*)(w + 51200);                          // 18432 B
    float* xbuf    = (float*)(w + 51200 + 18432);                // 4608*588 f32
    ushort_t* hbuf = (ushort_t*)(xbuf + (size_t)B_ * NP_ * PK_); // 4608*1024 bf16
    ushort_t* g1   = hbuf + (size_t)B_ * NP_ * DV_;              // 4608*4096 bf16
    ushort_t* w1t  = g1 + (size_t)B_ * NP_ * D_;                 // 4096*1024 bf16
    ushort_t* w2t  = w1t + (size_t)D_ * DV_;                     // 4096*4096 bf16

    fill_tail_kernel<<<2048, 256, 0, stream>>>(out);
    merge_kernel<<<1, 512, 0, stream>>>(input_ids, attn, labels, out, src_index, img_pos);

    {
        int total = B_ * NP_ * PK_;
        patchify_kernel<<<(total + 255) / 256, 256, 0, stream>>>(pixel, xbuf);
    }
    // weight converts: w1 (DVxD) -> w1t (DxDV), w2 (DxD) -> w2t (DxD)
    transpose_bf16_kernel<<<dim3(D_ / 32, DV_ / 32), 256, 0, stream>>>(w1, w1t, DV_, D_);
    transpose_bf16_kernel<<<dim3(D_ / 32, D_ / 32), 256, 0, stream>>>(w2, w2t, D_, D_);

    const int M = B_ * NP_;  // 4608
    // GEMM1 (fp32, bf16 out): x(4608x588) @ patch_w(588x1024) + patch_b -> hbuf
    sgemm_kernel<<<dim3(DV_ / 128, (M + 127) / 128), 256, 0, stream>>>(
        xbuf, patch_w, patch_b, nullptr, hbuf, M, DV_, PK_, 3);
    // GEMM2 (MFMA): gelu(h @ w1 + b1) -> g1 bf16
    mfma_gemm_bt<<<dim3(D_ / 128, M / 128), 256, 0, stream>>>(
        hbuf, w1t, b1, g1, nullptr, nullptr, M, D_, DV_, 1);
    // GEMM3 (MFMA): g1 @ w2 + b2 -> scattered fp32 rows of final_emb
    mfma_gemm_bt<<<dim3(D_ / 128, M / 128), 256, 0, stream>>>(
        g1, w2t, b2, nullptr, out + OFF_EMB, img_pos, M, D_, D_, 2);

    scatter_text_kernel<<<B_ * MAXE_, 256, 0, stream>>>(src_index, input_ids, embed, out + OFF_EMB);
}